// Round 1
// baseline (645.221 us; speedup 1.0000x reference)
//
#include <hip/hip_runtime.h>
#include <math.h>

#define N_NODES 10000
#define N_EDGES 160000
#define TBL_N 2048              // intervals; TBL_N+1 rows of 256 channels
#define ACT_C 1.676518f         // 1/sqrt(E[silu(z)^2]), z~N(0,1)

// mix(x) lookup table: rebuilt deterministically every launch (no cross-call state relied on)
__device__ float g_table[(TBL_N + 1) * 256];

__global__ __launch_bounds__(256) void build_table(const float* __restrict__ W1,
                                                   const float* __restrict__ W2,
                                                   const float* __restrict__ W3) {
    __shared__ float h[4][64];
    const int lane = threadIdx.x & 63;
    const int wl = threadIdx.x >> 6;
    int wid = blockIdx.x * 4 + wl;
    if (wid > TBL_N) wid = TBL_N;   // clamp (duplicates write identical values; keeps barriers safe)
    const float x = (float)wid * (1.0f / (float)TBL_N);

    // radial = bessel(x) * envelope(x)
    float x2 = x * x, x3 = x2 * x, x6 = x3 * x3;
    float env = (x < 1.0f) ? (1.0f - 28.0f * x6 + 48.0f * x6 * x - 21.0f * x6 * x2) : 0.0f;
    const float pi = 3.14159265358979f;
    const float sqrt2 = 1.41421356237f;
    float radial[8];
    #pragma unroll
    for (int k = 1; k <= 8; ++k) {
        float b = (x == 0.0f) ? ((float)k * pi) : (sinf(pi * (float)k * x) / x);
        radial[k - 1] = sqrt2 * b * env;
    }
    // layer 1: h1[lane] = silu-scaled( radial @ W1 / sqrt(8) )
    float acc = 0.0f;
    #pragma unroll
    for (int k = 0; k < 8; ++k) acc += radial[k] * W1[k * 64 + lane];
    acc *= 0.35355339059f;      // 1/sqrt(8)
    float a = ACT_C * acc / (1.0f + expf(-acc));   // ACT_C * silu(acc)
    h[wl][lane] = a;
    __syncthreads();
    // layer 2
    acc = 0.0f;
    #pragma unroll 8
    for (int k = 0; k < 64; ++k) acc += h[wl][k] * W2[k * 64 + lane];
    acc *= 0.125f;              // 1/sqrt(64)
    a = ACT_C * acc / (1.0f + expf(-acc));
    __syncthreads();
    h[wl][lane] = a;
    __syncthreads();
    // layer 3: 4 chunks of 64 outputs
    float m0 = 0.f, m1 = 0.f, m2 = 0.f, m3 = 0.f;
    #pragma unroll 4
    for (int k = 0; k < 64; ++k) {
        float hk = h[wl][k];
        const float* w = W3 + k * 256 + lane;
        m0 += hk * w[0];
        m1 += hk * w[64];
        m2 += hk * w[128];
        m3 += hk * w[192];
    }
    float* T = g_table + wid * 256 + lane;
    T[0]   = m0 * 0.125f;
    T[64]  = m1 * 0.125f;
    T[128] = m2 * 0.125f;
    T[192] = m3 * 0.125f;
}

__global__ __launch_bounds__(256) void edge_kernel(const float* __restrict__ vectors,
                                                   const float* __restrict__ node_scalars,
                                                   const float* __restrict__ node_vectors,
                                                   const int* __restrict__ senders,
                                                   const int* __restrict__ receivers,
                                                   float* __restrict__ out) {
    const int u = threadIdx.x & 63;                       // channel lane 0..63
    const int e = (int)((blockIdx.x * 256u + threadIdx.x) >> 6);  // wave-per-edge
    if (e >= N_EDGES) return;

    const float vx = vectors[e * 3 + 0];
    const float vy = vectors[e * 3 + 1];
    const float vz = vectors[e * 3 + 2];
    const float x = sqrtf(vx * vx + vy * vy + vz * vz);
    if (x >= 1.0f) return;    // envelope==0 -> mix==0 -> zero contribution (uniform branch)

    const int sv = senders[e];
    const int rv = receivers[e];

    // interpolate mix channels u, 64+u, 128+u, 192+u
    const float t = x * (float)TBL_N;
    int i = (int)t;
    if (i > TBL_N - 1) i = TBL_N - 1;
    const float f = t - (float)i;
    const float* T0 = g_table + i * 256 + u;
    const float* T1 = T0 + 256;
    const float mA = fmaf(f, T1[0]   - T0[0],   T0[0]);
    const float mB = fmaf(f, T1[64]  - T0[64],  T0[64]);
    const float mC = fmaf(f, T1[128] - T0[128], T0[128]);
    const float mD = fmaf(f, T1[192] - T0[192], T0[192]);

    // gather sender features (coalesced across wave)
    const float m0u = node_scalars[sv * 64 + u];
    const float* m1p = node_vectors + sv * 192 + 3 * u;
    const float m1x = m1p[0], m1y = m1p[1], m1z = m1p[2];

    const float invx = 1.0f / x;
    const float tp0 = (m1x * vx + m1y * vy + m1z * vz) * invx;   // (m1 . Y1)/sqrt(3)
    const float s3 = 1.7320508075688772f;
    const float Yx = s3 * vx * invx, Yy = s3 * vy * invx, Yz = s3 * vz * invx;

    const float inv = 0.25f;    // 1/sqrt(AVG_NEIGH)
    float* o = out + (size_t)rv * 512;
    unsafeAtomicAdd(o + u,        inv * m0u * mA);
    unsafeAtomicAdd(o + 64 + u,   inv * tp0 * mB);
    const float cC = inv * mC;
    unsafeAtomicAdd(o + 128 + 3 * u + 0, cC * m1x);
    unsafeAtomicAdd(o + 128 + 3 * u + 1, cC * m1y);
    unsafeAtomicAdd(o + 128 + 3 * u + 2, cC * m1z);
    const float cD = inv * m0u * mD;
    unsafeAtomicAdd(o + 320 + 3 * u + 0, cD * Yx);
    unsafeAtomicAdd(o + 320 + 3 * u + 1, cD * Yy);
    unsafeAtomicAdd(o + 320 + 3 * u + 2, cD * Yz);
}

extern "C" void kernel_launch(void* const* d_in, const int* in_sizes, int n_in,
                              void* d_out, int out_size, void* d_ws, size_t ws_size,
                              hipStream_t stream) {
    const float* vectors      = (const float*)d_in[0];
    const float* node_scalars = (const float*)d_in[1];
    const float* node_vectors = (const float*)d_in[2];
    const int*   senders      = (const int*)d_in[3];
    const int*   receivers    = (const int*)d_in[4];
    const float* W1           = (const float*)d_in[5];
    const float* W2           = (const float*)d_in[6];
    const float* W3           = (const float*)d_in[7];
    float* out = (float*)d_out;

    hipMemsetAsync(d_out, 0, (size_t)out_size * sizeof(float), stream);

    build_table<<<(TBL_N + 1 + 3) / 4, 256, 0, stream>>>(W1, W2, W3);

    const int edge_blocks = (N_EDGES * 64 + 255) / 256;   // wave-per-edge
    edge_kernel<<<edge_blocks, 256, 0, stream>>>(vectors, node_scalars, node_vectors,
                                                 senders, receivers, out);
}

// Round 2
// 107.737 us; speedup vs baseline: 5.9888x; 5.9888x over previous
//
#include <hip/hip_runtime.h>
#include <math.h>

#define N_NODES 10000
#define N_EDGES 160000
#define TBL_N 2048              // intervals; TBL_N+1 rows
#define ACT_C 1.676518f         // 1/sqrt(E[silu(z)^2]), z~N(0,1)

// Per-lane-packed mix table: row i, lane u -> {mixA, mixB, mixC, mixD} for channel u
__device__ float4 g_table[(TBL_N + 1) * 64];
// CSR by receiver (rebuilt deterministically every launch)
__device__ int    g_off[N_NODES + 1];
__device__ int    g_cur[N_NODES];
__device__ float4 g_rec[N_EDGES];   // {vx, vy, vz, bitcast(sender)} at sorted slot

__global__ __launch_bounds__(256) void zero_cur() {
    int i = blockIdx.x * 256 + threadIdx.x;
    if (i < N_NODES) g_cur[i] = 0;
}

__global__ __launch_bounds__(256) void hist_kernel(const float* __restrict__ vectors,
                                                   const int* __restrict__ receivers) {
    int e = blockIdx.x * 256 + threadIdx.x;
    if (e >= N_EDGES) return;
    float vx = vectors[3 * e], vy = vectors[3 * e + 1], vz = vectors[3 * e + 2];
    float x2 = vx * vx + vy * vy + vz * vz;
    if (x2 < 1.0f) atomicAdd(&g_cur[receivers[e]], 1);   // envelope==0 edges dropped
}

__global__ __launch_bounds__(256) void scan_kernel() {
    __shared__ int part[256];
    const int t = threadIdx.x;
    const int chunk = (N_NODES + 255) / 256;             // 40
    int beg = t * chunk;
    int end = beg + chunk; if (end > N_NODES) end = N_NODES;
    int s = 0;
    for (int i = beg; i < end; ++i) s += g_cur[i];
    part[t] = s;
    __syncthreads();
    for (int off = 1; off < 256; off <<= 1) {
        int v = (t >= off) ? part[t - off] : 0;
        __syncthreads();
        part[t] += v;
        __syncthreads();
    }
    int run = (t == 0) ? 0 : part[t - 1];                // exclusive prefix of this chunk
    for (int i = beg; i < end; ++i) {
        int c = g_cur[i];
        g_off[i] = run;
        g_cur[i] = run;                                  // cursor for scatter
        run += c;
    }
    if (t == 0) g_off[N_NODES] = part[255];
}

__global__ __launch_bounds__(256) void scatter_kernel(const float* __restrict__ vectors,
                                                      const int* __restrict__ senders,
                                                      const int* __restrict__ receivers) {
    int e = blockIdx.x * 256 + threadIdx.x;
    if (e >= N_EDGES) return;
    float vx = vectors[3 * e], vy = vectors[3 * e + 1], vz = vectors[3 * e + 2];
    float x2 = vx * vx + vy * vy + vz * vz;
    if (x2 >= 1.0f) return;
    int slot = atomicAdd(&g_cur[receivers[e]], 1);
    g_rec[slot] = make_float4(vx, vy, vz, __int_as_float(senders[e]));
}

__global__ __launch_bounds__(256) void build_table(const float* __restrict__ W1,
                                                   const float* __restrict__ W2,
                                                   const float* __restrict__ W3) {
    __shared__ float h[4][64];
    const int lane = threadIdx.x & 63;
    const int wl = threadIdx.x >> 6;
    int wid = blockIdx.x * 4 + wl;
    if (wid > TBL_N) wid = TBL_N;   // clamp (duplicates write identical values; keeps barriers safe)
    const float x = (float)wid * (1.0f / (float)TBL_N);

    float x2 = x * x, x3 = x2 * x, x6 = x3 * x3;
    float env = (x < 1.0f) ? (1.0f - 28.0f * x6 + 48.0f * x6 * x - 21.0f * x6 * x2) : 0.0f;
    const float pi = 3.14159265358979f;
    const float sqrt2 = 1.41421356237f;
    float radial[8];
    #pragma unroll
    for (int k = 1; k <= 8; ++k) {
        float b = (x == 0.0f) ? ((float)k * pi) : (sinf(pi * (float)k * x) / x);
        radial[k - 1] = sqrt2 * b * env;
    }
    float acc = 0.0f;
    #pragma unroll
    for (int k = 0; k < 8; ++k) acc += radial[k] * W1[k * 64 + lane];
    acc *= 0.35355339059f;      // 1/sqrt(8)
    float a = ACT_C * acc / (1.0f + expf(-acc));
    h[wl][lane] = a;
    __syncthreads();
    acc = 0.0f;
    #pragma unroll 8
    for (int k = 0; k < 64; ++k) acc += h[wl][k] * W2[k * 64 + lane];
    acc *= 0.125f;              // 1/sqrt(64)
    a = ACT_C * acc / (1.0f + expf(-acc));
    __syncthreads();
    h[wl][lane] = a;
    __syncthreads();
    float m0 = 0.f, m1 = 0.f, m2 = 0.f, m3 = 0.f;
    #pragma unroll 4
    for (int k = 0; k < 64; ++k) {
        float hk = h[wl][k];
        const float* w = W3 + k * 256 + lane;
        m0 += hk * w[0];
        m1 += hk * w[64];
        m2 += hk * w[128];
        m3 += hk * w[192];
    }
    // packed store: lane u holds channels {u, 64+u, 128+u, 192+u}
    g_table[wid * 64 + lane] = make_float4(m0 * 0.125f, m1 * 0.125f, m2 * 0.125f, m3 * 0.125f);
}

__global__ __launch_bounds__(256) void gather_kernel(const float* __restrict__ node_scalars,
                                                     const float* __restrict__ node_vectors,
                                                     float* __restrict__ out) {
    const int u = threadIdx.x & 63;
    const int n = (int)((blockIdx.x * 256u + threadIdx.x) >> 6);   // wave-per-node
    if (n >= N_NODES) return;
    const int beg = g_off[n];
    const int end = g_off[n + 1];

    float accA = 0.f, accB = 0.f;
    float aCx = 0.f, aCy = 0.f, aCz = 0.f;
    float aDx = 0.f, aDy = 0.f, aDz = 0.f;

    for (int j = beg; j < end; ++j) {
        float4 r = g_rec[j];                       // broadcast load (wave-uniform addr)
        float vx = r.x, vy = r.y, vz = r.z;
        int sv = __float_as_int(r.w);

        float x = sqrtf(vx * vx + vy * vy + vz * vz);
        float t = x * (float)TBL_N;
        int i = (int)t; if (i > TBL_N - 1) i = TBL_N - 1;
        float f = t - (float)i;
        float4 t0 = g_table[i * 64 + u];           // coalesced 1KB/wave
        float4 t1 = g_table[i * 64 + 64 + u];
        float mA = fmaf(f, t1.x - t0.x, t0.x);
        float mB = fmaf(f, t1.y - t0.y, t0.y);
        float mC = fmaf(f, t1.z - t0.z, t0.z);
        float mD = fmaf(f, t1.w - t0.w, t0.w);

        float m0u = node_scalars[sv * 64 + u];     // coalesced 256B gather
        const float* p = node_vectors + sv * 192 + 3 * u;
        float m1x = p[0], m1y = p[1], m1z = p[2];  // coalesced 768B gather

        float invx = 1.0f / x;
        float tp0 = (m1x * vx + m1y * vy + m1z * vz) * invx;

        accA += m0u * mA;
        accB += tp0 * mB;
        aCx += mC * m1x; aCy += mC * m1y; aCz += mC * m1z;
        float cD = m0u * mD * 1.7320508075688772f * invx;
        aDx += cD * vx; aDy += cD * vy; aDz += cD * vz;
    }

    const float inv = 0.25f;    // 1/sqrt(AVG_NEIGH)
    float* o = out + (size_t)n * 512;
    o[u]       = inv * accA;
    o[64 + u]  = inv * accB;
    o[128 + 3 * u + 0] = inv * aCx;
    o[128 + 3 * u + 1] = inv * aCy;
    o[128 + 3 * u + 2] = inv * aCz;
    o[320 + 3 * u + 0] = inv * aDx;
    o[320 + 3 * u + 1] = inv * aDy;
    o[320 + 3 * u + 2] = inv * aDz;
}

extern "C" void kernel_launch(void* const* d_in, const int* in_sizes, int n_in,
                              void* d_out, int out_size, void* d_ws, size_t ws_size,
                              hipStream_t stream) {
    const float* vectors      = (const float*)d_in[0];
    const float* node_scalars = (const float*)d_in[1];
    const float* node_vectors = (const float*)d_in[2];
    const int*   senders      = (const int*)d_in[3];
    const int*   receivers    = (const int*)d_in[4];
    const float* W1           = (const float*)d_in[5];
    const float* W2           = (const float*)d_in[6];
    const float* W3           = (const float*)d_in[7];
    float* out = (float*)d_out;

    zero_cur<<<(N_NODES + 255) / 256, 256, 0, stream>>>();
    hist_kernel<<<(N_EDGES + 255) / 256, 256, 0, stream>>>(vectors, receivers);
    scan_kernel<<<1, 256, 0, stream>>>();
    scatter_kernel<<<(N_EDGES + 255) / 256, 256, 0, stream>>>(vectors, senders, receivers);
    build_table<<<(TBL_N + 1 + 3) / 4, 256, 0, stream>>>(W1, W2, W3);

    const int gather_blocks = (N_NODES * 64 + 255) / 256;   // wave-per-node
    gather_kernel<<<gather_blocks, 256, 0, stream>>>(node_scalars, node_vectors, out);
    // out fully written per node (all 512 channels) -> no memset needed
}

// Round 3
// 68.966 us; speedup vs baseline: 9.3556x; 1.5622x over previous
//
#include <hip/hip_runtime.h>
#include <math.h>

#define N_NODES 10000
#define N_EDGES 160000
#define TBL_N 2048              // intervals; TBL_N+1 rows
#define ACT_C 1.676518f         // 1/sqrt(E[silu(z)^2]), z~N(0,1)
#define CAP 64                  // bucket capacity per node (mean valid degree ~15.4; P(>64)~e^-40)
#define S3 1.7320508075688772f

// Per-lane-packed mix table: row i, lane u -> {mixA, mixB, mixC, mixD} for channel u
__device__ float4 g_table[(TBL_N + 1) * 64];
// Fixed-capacity edge buckets by receiver (rebuilt deterministically every launch)
__device__ int    g_cnt[N_NODES];
__device__ float4 g_bkt[N_NODES * CAP];    // {yhat_x, yhat_y, yhat_z, t = x*TBL_N}
__device__ int    g_snd[N_NODES * CAP];    // sender index

#define TBL_BLOCKS 513          // 513 blocks * 4 waves = 2052 >= 2049 rows

// Fused: build mix table (blocks [0,513)) + zero bucket counters (blocks [513, 513+40))
__global__ __launch_bounds__(256) void prep_kernel(const float* __restrict__ W1,
                                                   const float* __restrict__ W2,
                                                   const float* __restrict__ W3) {
    if (blockIdx.x >= TBL_BLOCKS) {
        int i = (blockIdx.x - TBL_BLOCKS) * 256 + threadIdx.x;
        if (i < N_NODES) g_cnt[i] = 0;
        return;
    }
    __shared__ float h[4][64];
    const int lane = threadIdx.x & 63;
    const int wl = threadIdx.x >> 6;
    int wid = blockIdx.x * 4 + wl;
    if (wid > TBL_N) wid = TBL_N;   // clamp (duplicates write identical values; keeps barriers safe)
    const float x = (float)wid * (1.0f / (float)TBL_N);

    float x2 = x * x, x3 = x2 * x, x6 = x3 * x3;
    float env = (x < 1.0f) ? (1.0f - 28.0f * x6 + 48.0f * x6 * x - 21.0f * x6 * x2) : 0.0f;
    const float pi = 3.14159265358979f;
    const float sqrt2 = 1.41421356237f;
    float radial[8];
    #pragma unroll
    for (int k = 1; k <= 8; ++k) {
        float b = (x == 0.0f) ? ((float)k * pi) : (sinf(pi * (float)k * x) / x);
        radial[k - 1] = sqrt2 * b * env;
    }
    float acc = 0.0f;
    #pragma unroll
    for (int k = 0; k < 8; ++k) acc += radial[k] * W1[k * 64 + lane];
    acc *= 0.35355339059f;      // 1/sqrt(8)
    float a = ACT_C * acc / (1.0f + expf(-acc));
    h[wl][lane] = a;
    __syncthreads();
    acc = 0.0f;
    #pragma unroll 8
    for (int k = 0; k < 64; ++k) acc += h[wl][k] * W2[k * 64 + lane];
    acc *= 0.125f;              // 1/sqrt(64)
    a = ACT_C * acc / (1.0f + expf(-acc));
    __syncthreads();
    h[wl][lane] = a;
    __syncthreads();
    float m0 = 0.f, m1 = 0.f, m2 = 0.f, m3 = 0.f;
    #pragma unroll 4
    for (int k = 0; k < 64; ++k) {
        float hk = h[wl][k];
        const float* w = W3 + k * 256 + lane;
        m0 += hk * w[0];
        m1 += hk * w[64];
        m2 += hk * w[128];
        m3 += hk * w[192];
    }
    // packed store: lane u holds channels {u, 64+u, 128+u, 192+u}
    g_table[wid * 64 + lane] = make_float4(m0 * 0.125f, m1 * 0.125f, m2 * 0.125f, m3 * 0.125f);
}

__global__ __launch_bounds__(256) void scatter_kernel(const float* __restrict__ vectors,
                                                      const int* __restrict__ senders,
                                                      const int* __restrict__ receivers) {
    int e = blockIdx.x * 256 + threadIdx.x;
    if (e >= N_EDGES) return;
    float vx = vectors[3 * e], vy = vectors[3 * e + 1], vz = vectors[3 * e + 2];
    float x2 = vx * vx + vy * vy + vz * vz;
    if (x2 >= 1.0f) return;                 // envelope==0 -> zero contribution
    float x = sqrtf(x2);
    float invx = 1.0f / x;
    int r = receivers[e];
    int slot = atomicAdd(&g_cnt[r], 1);
    if (slot < CAP) {                       // overflow-safe clamp (never taken in practice)
        g_bkt[(r << 6) + slot] = make_float4(vx * invx, vy * invx, vz * invx, x * (float)TBL_N);
        g_snd[(r << 6) + slot] = senders[e];
    }
}

__global__ __launch_bounds__(256) void gather_kernel(const float* __restrict__ node_scalars,
                                                     const float* __restrict__ node_vectors,
                                                     float* __restrict__ out) {
    const int u = threadIdx.x & 63;
    const int n = (int)((blockIdx.x * 256u + threadIdx.x) >> 6);   // wave-per-node
    if (n >= N_NODES) return;
    const int base = n << 6;
    int cnt = g_cnt[n]; if (cnt > CAP) cnt = CAP;

    // hoist: lane u holds edge u's record; broadcast later via shuffles (no memory latency)
    const int hidx = base + (u < cnt ? u : 0);     // in-bounds guard; unused when cnt==0
    const float4 myrec = g_bkt[hidx];
    const int   mysnd = g_snd[hidx];

    float accA = 0.f, accB = 0.f;
    float aCx = 0.f, aCy = 0.f, aCz = 0.f;
    float aDx = 0.f, aDy = 0.f, aDz = 0.f;

    int j = 0;
    for (; j + 4 <= cnt; j += 4) {
        float yx[4], yy[4], yz[4], f[4], m0u[4], m1x[4], m1y[4], m1z[4];
        float4 t0[4], t1[4];
        #pragma unroll
        for (int k = 0; k < 4; ++k) {
            const int jj = j + k;
            yx[k] = __shfl(myrec.x, jj);
            yy[k] = __shfl(myrec.y, jj);
            yz[k] = __shfl(myrec.z, jj);
            float t = __shfl(myrec.w, jj);
            int sv  = __shfl(mysnd, jj);
            int i = (int)t;                    // t < 2048 guaranteed (x < 1)
            f[k] = t - (float)i;
            t0[k] = g_table[i * 64 + u];       // coalesced 1KB/wave, L2-hot
            t1[k] = g_table[i * 64 + 64 + u];
            m0u[k] = node_scalars[sv * 64 + u];
            const float* p = node_vectors + sv * 192 + 3 * u;
            m1x[k] = p[0]; m1y[k] = p[1]; m1z[k] = p[2];
        }
        #pragma unroll
        for (int k = 0; k < 4; ++k) {
            float mA = fmaf(f[k], t1[k].x - t0[k].x, t0[k].x);
            float mB = fmaf(f[k], t1[k].y - t0[k].y, t0[k].y);
            float mC = fmaf(f[k], t1[k].z - t0[k].z, t0[k].z);
            float mD = fmaf(f[k], t1[k].w - t0[k].w, t0[k].w);
            float tp0 = fmaf(m1x[k], yx[k], fmaf(m1y[k], yy[k], m1z[k] * yz[k]));
            accA = fmaf(m0u[k], mA, accA);
            accB = fmaf(tp0, mB, accB);
            aCx = fmaf(mC, m1x[k], aCx);
            aCy = fmaf(mC, m1y[k], aCy);
            aCz = fmaf(mC, m1z[k], aCz);
            float cD = m0u[k] * mD * S3;
            aDx = fmaf(cD, yx[k], aDx);
            aDy = fmaf(cD, yy[k], aDy);
            aDz = fmaf(cD, yz[k], aDz);
        }
    }
    for (; j < cnt; ++j) {
        float yx = __shfl(myrec.x, j);
        float yy = __shfl(myrec.y, j);
        float yz = __shfl(myrec.z, j);
        float t  = __shfl(myrec.w, j);
        int sv   = __shfl(mysnd, j);
        int i = (int)t;
        float f = t - (float)i;
        float4 t0 = g_table[i * 64 + u];
        float4 t1 = g_table[i * 64 + 64 + u];
        float mA = fmaf(f, t1.x - t0.x, t0.x);
        float mB = fmaf(f, t1.y - t0.y, t0.y);
        float mC = fmaf(f, t1.z - t0.z, t0.z);
        float mD = fmaf(f, t1.w - t0.w, t0.w);
        float m0u = node_scalars[sv * 64 + u];
        const float* p = node_vectors + sv * 192 + 3 * u;
        float m1x = p[0], m1y = p[1], m1z = p[2];
        float tp0 = fmaf(m1x, yx, fmaf(m1y, yy, m1z * yz));
        accA = fmaf(m0u, mA, accA);
        accB = fmaf(tp0, mB, accB);
        aCx = fmaf(mC, m1x, aCx);
        aCy = fmaf(mC, m1y, aCy);
        aCz = fmaf(mC, m1z, aCz);
        float cD = m0u * mD * S3;
        aDx = fmaf(cD, yx, aDx);
        aDy = fmaf(cD, yy, aDy);
        aDz = fmaf(cD, yz, aDz);
    }

    const float inv = 0.25f;    // 1/sqrt(AVG_NEIGH)
    float* o = out + (size_t)n * 512;
    o[u]       = inv * accA;
    o[64 + u]  = inv * accB;
    o[128 + 3 * u + 0] = inv * aCx;
    o[128 + 3 * u + 1] = inv * aCy;
    o[128 + 3 * u + 2] = inv * aCz;
    o[320 + 3 * u + 0] = inv * aDx;
    o[320 + 3 * u + 1] = inv * aDy;
    o[320 + 3 * u + 2] = inv * aDz;
}

extern "C" void kernel_launch(void* const* d_in, const int* in_sizes, int n_in,
                              void* d_out, int out_size, void* d_ws, size_t ws_size,
                              hipStream_t stream) {
    const float* vectors      = (const float*)d_in[0];
    const float* node_scalars = (const float*)d_in[1];
    const float* node_vectors = (const float*)d_in[2];
    const int*   senders      = (const int*)d_in[3];
    const int*   receivers    = (const int*)d_in[4];
    const float* W1           = (const float*)d_in[5];
    const float* W2           = (const float*)d_in[6];
    const float* W3           = (const float*)d_in[7];
    float* out = (float*)d_out;

    const int zero_blocks = (N_NODES + 255) / 256;          // 40
    prep_kernel<<<TBL_BLOCKS + zero_blocks, 256, 0, stream>>>(W1, W2, W3);
    scatter_kernel<<<(N_EDGES + 255) / 256, 256, 0, stream>>>(vectors, senders, receivers);

    const int gather_blocks = (N_NODES * 64 + 255) / 256;   // wave-per-node
    gather_kernel<<<gather_blocks, 256, 0, stream>>>(node_scalars, node_vectors, out);
    // out fully written per node (all 512 channels) -> no memset needed
}

// Round 4
// 51.833 us; speedup vs baseline: 12.4481x; 1.3306x over previous
//
#include <hip/hip_runtime.h>
#include <hip/hip_fp16.h>
#include <math.h>

#define N_NODES 10000
#define N_EDGES 160000
#define TBL_N 512               // intervals; TBL_N+1 rows (interp err ~3e-4, fp16 ~5e-4: fine vs 1.3 thr)
#define ACT_C 1.676518f         // 1/sqrt(E[silu(z)^2]), z~N(0,1)
#define CAP 64                  // bucket capacity per node (mean valid degree ~15.4; P(>64)~e^-40)
#define S3 1.7320508075688772f

// mix table, fp16-packed: lane u holds {half2(mA,mB), half2(mC,mD)} for channels {u,64+u,128+u,192+u}
__device__ uint2  g_tbl[(TBL_N + 1) * 64];
// per-node fp16 features: [0,64): m0 | [64,192): (vx,vy) half2 per channel | [192,256): vz
__device__ __half g_nd[N_NODES * 256];
__device__ int    g_cnt[N_NODES];
// bucket record: {yhat_x, yhat_y, yhat_z, bits = sender<<18 | idx<<9 | frac9}
__device__ float4 g_bkt[N_NODES * CAP];

#define TBL_BLOCKS  129         // 516 waves >= 513 rows
#define CONV_BLOCKS 2500        // 4 nodes per block (wave-per-node)
#define ZERO_BLOCKS 40

// Fused prep: table MLP + fp16 node-feature convert + counter zero (role by blockIdx)
__global__ __launch_bounds__(256) void prep_kernel(const float* __restrict__ W1,
                                                   const float* __restrict__ W2,
                                                   const float* __restrict__ W3,
                                                   const float* __restrict__ node_scalars,
                                                   const float* __restrict__ node_vectors) {
    const int lane = threadIdx.x & 63;
    const int wl = threadIdx.x >> 6;

    if (blockIdx.x >= TBL_BLOCKS) {
        int b = blockIdx.x - TBL_BLOCKS;
        if (b < CONV_BLOCKS) {
            // convert node n's features to fp16, transposed layout
            int n = b * 4 + wl;                       // exactly covers [0,10000)
            float m0 = node_scalars[n * 64 + lane];
            const float* p = node_vectors + n * 192 + 3 * lane;
            float vx = p[0], vy = p[1], vz = p[2];
            __half* nd = g_nd + n * 256;
            nd[lane] = __float2half(m0);
            *(__half2*)(nd + 64 + 2 * lane) = __floats2half2_rn(vx, vy);
            nd[192 + lane] = __float2half(vz);
        } else {
            int i = (b - CONV_BLOCKS) * 256 + threadIdx.x;
            if (i < N_NODES) g_cnt[i] = 0;
        }
        return;
    }

    // ---- mix table build (blocks [0,129), wave-per-row) ----
    __shared__ float h[4][64];
    int wid = blockIdx.x * 4 + wl;
    if (wid > TBL_N) wid = TBL_N;   // clamp (duplicates write identical values; keeps barriers safe)
    const float x = (float)wid * (1.0f / (float)TBL_N);

    float x2 = x * x, x3 = x2 * x, x6 = x3 * x3;
    float env = (x < 1.0f) ? (1.0f - 28.0f * x6 + 48.0f * x6 * x - 21.0f * x6 * x2) : 0.0f;
    const float pi = 3.14159265358979f;
    const float sqrt2 = 1.41421356237f;
    float radial[8];
    #pragma unroll
    for (int k = 1; k <= 8; ++k) {
        float b = (x == 0.0f) ? ((float)k * pi) : (sinf(pi * (float)k * x) / x);
        radial[k - 1] = sqrt2 * b * env;
    }
    float acc = 0.0f;
    #pragma unroll
    for (int k = 0; k < 8; ++k) acc += radial[k] * W1[k * 64 + lane];
    acc *= 0.35355339059f;      // 1/sqrt(8)
    float a = ACT_C * acc / (1.0f + expf(-acc));
    h[wl][lane] = a;
    __syncthreads();
    acc = 0.0f;
    #pragma unroll 8
    for (int k = 0; k < 64; ++k) acc += h[wl][k] * W2[k * 64 + lane];
    acc *= 0.125f;              // 1/sqrt(64)
    a = ACT_C * acc / (1.0f + expf(-acc));
    __syncthreads();
    h[wl][lane] = a;
    __syncthreads();
    float m0 = 0.f, m1 = 0.f, m2 = 0.f, m3 = 0.f;
    #pragma unroll 4
    for (int k = 0; k < 64; ++k) {
        float hk = h[wl][k];
        const float* w = W3 + k * 256 + lane;
        m0 += hk * w[0];
        m1 += hk * w[64];
        m2 += hk * w[128];
        m3 += hk * w[192];
    }
    __half2 h01 = __floats2half2_rn(m0 * 0.125f, m1 * 0.125f);
    __half2 h23 = __floats2half2_rn(m2 * 0.125f, m3 * 0.125f);
    uint2 r;
    r.x = *(unsigned int*)&h01;
    r.y = *(unsigned int*)&h23;
    g_tbl[wid * 64 + lane] = r;
}

__global__ __launch_bounds__(256) void scatter_kernel(const float* __restrict__ vectors,
                                                      const int* __restrict__ senders,
                                                      const int* __restrict__ receivers) {
    int e = blockIdx.x * 256 + threadIdx.x;
    if (e >= N_EDGES) return;
    float vx = vectors[3 * e], vy = vectors[3 * e + 1], vz = vectors[3 * e + 2];
    float x2 = vx * vx + vy * vy + vz * vz;
    if (x2 >= 1.0f) return;                 // envelope==0 -> zero contribution
    float invx = rsqrtf(x2);
    float x = x2 * invx;
    float t = x * (float)TBL_N;
    int idx = (int)t;            if (idx > TBL_N - 1) idx = TBL_N - 1;
    int fr  = (int)((t - (float)idx) * 512.0f);  if (fr > 511) fr = 511;
    unsigned int bits = ((unsigned int)senders[e] << 18) | ((unsigned int)idx << 9) | (unsigned int)fr;
    int r = receivers[e];
    int slot = atomicAdd(&g_cnt[r], 1);
    if (slot < CAP) {                       // overflow-safe clamp (never taken in practice)
        g_bkt[(r << 6) + slot] = make_float4(vx * invx, vy * invx, vz * invx, __uint_as_float(bits));
    }
}

__device__ __forceinline__ void edge_body(int j, const float4& myrec,
                                          int u, float& accA, float& accB,
                                          float& aCx, float& aCy, float& aCz,
                                          float& aDx, float& aDy, float& aDz) {
    float yx = __shfl(myrec.x, j);
    float yy = __shfl(myrec.y, j);
    float yz = __shfl(myrec.z, j);
    unsigned int bits = __float_as_uint(__shfl(myrec.w, j));
    int sv = (int)(bits >> 18);
    int i  = (int)((bits >> 9) & 511u);
    float f = (float)(bits & 511u) * (1.0f / 512.0f);

    uint2 q0 = g_tbl[i * 64 + u];           // coalesced 512B/wave, L2-resident
    uint2 q1 = g_tbl[i * 64 + 64 + u];
    const __half* nd = g_nd + sv * 256;
    float m0u = __half2float(nd[u]);
    float2 vxy = __half22float2(*(const __half2*)(nd + 64 + 2 * u));
    float vz_ = __half2float(nd[192 + u]);

    float2 a0 = __half22float2(*(__half2*)&q0.x);   // (mA, mB) at row i
    float2 b0 = __half22float2(*(__half2*)&q0.y);   // (mC, mD)
    float2 a1 = __half22float2(*(__half2*)&q1.x);
    float2 b1 = __half22float2(*(__half2*)&q1.y);
    float mA = fmaf(f, a1.x - a0.x, a0.x);
    float mB = fmaf(f, a1.y - a0.y, a0.y);
    float mC = fmaf(f, b1.x - b0.x, b0.x);
    float mD = fmaf(f, b1.y - b0.y, b0.y);

    float tp0 = fmaf(vxy.x, yx, fmaf(vxy.y, yy, vz_ * yz));
    accA = fmaf(m0u, mA, accA);
    accB = fmaf(tp0, mB, accB);
    aCx = fmaf(mC, vxy.x, aCx);
    aCy = fmaf(mC, vxy.y, aCy);
    aCz = fmaf(mC, vz_,   aCz);
    float cD = m0u * mD * S3;
    aDx = fmaf(cD, yx, aDx);
    aDy = fmaf(cD, yy, aDy);
    aDz = fmaf(cD, yz, aDz);
}

__global__ __launch_bounds__(256) void gather_kernel(float* __restrict__ out) {
    const int u = threadIdx.x & 63;
    const int n = (int)((blockIdx.x * 256u + threadIdx.x) >> 6);   // wave-per-node
    if (n >= N_NODES) return;
    const int base = n << 6;
    int cnt = g_cnt[n]; if (cnt > CAP) cnt = CAP;

    // hoist: lane u holds edge u's record; broadcast via shuffles (register, no memory latency)
    const float4 myrec = g_bkt[base + (u < cnt ? u : 0)];

    float accA = 0.f, accB = 0.f;
    float aCx = 0.f, aCy = 0.f, aCz = 0.f;
    float aDx = 0.f, aDy = 0.f, aDz = 0.f;

    int j = 0;
    for (; j + 2 <= cnt; j += 2) {          // 2-wide: ~12 independent loads in flight, VGPR ~40
        edge_body(j,     myrec, u, accA, accB, aCx, aCy, aCz, aDx, aDy, aDz);
        edge_body(j + 1, myrec, u, accA, accB, aCx, aCy, aCz, aDx, aDy, aDz);
    }
    if (j < cnt)
        edge_body(j,     myrec, u, accA, accB, aCx, aCy, aCz, aDx, aDy, aDz);

    const float inv = 0.25f;    // 1/sqrt(AVG_NEIGH)
    float* o = out + (size_t)n * 512;
    o[u]       = inv * accA;
    o[64 + u]  = inv * accB;
    o[128 + 3 * u + 0] = inv * aCx;
    o[128 + 3 * u + 1] = inv * aCy;
    o[128 + 3 * u + 2] = inv * aCz;
    o[320 + 3 * u + 0] = inv * aDx;
    o[320 + 3 * u + 1] = inv * aDy;
    o[320 + 3 * u + 2] = inv * aDz;
}

extern "C" void kernel_launch(void* const* d_in, const int* in_sizes, int n_in,
                              void* d_out, int out_size, void* d_ws, size_t ws_size,
                              hipStream_t stream) {
    const float* vectors      = (const float*)d_in[0];
    const float* node_scalars = (const float*)d_in[1];
    const float* node_vectors = (const float*)d_in[2];
    const int*   senders      = (const int*)d_in[3];
    const int*   receivers    = (const int*)d_in[4];
    const float* W1           = (const float*)d_in[5];
    const float* W2           = (const float*)d_in[6];
    const float* W3           = (const float*)d_in[7];
    float* out = (float*)d_out;

    prep_kernel<<<TBL_BLOCKS + CONV_BLOCKS + ZERO_BLOCKS, 256, 0, stream>>>(
        W1, W2, W3, node_scalars, node_vectors);
    scatter_kernel<<<(N_EDGES + 255) / 256, 256, 0, stream>>>(vectors, senders, receivers);

    const int gather_blocks = (N_NODES * 64 + 255) / 256;   // wave-per-node
    gather_kernel<<<gather_blocks, 256, 0, stream>>>(out);
    // out fully written per node (all 512 channels) -> no memset needed
}